// Round 2
// baseline (4617.035 us; speedup 1.0000x reference)
//
#include <hip/hip_runtime.h>
#include <hip/hip_bf16.h>

#define B_ 64
#define T_ 200
#define E_ 512
#define H_ 8
#define D_ 64

static constexpr float SCALE = 0.044194173824159216f;  // 512^-0.5

// ---------------- LayerNorm over E=512, one block per (b,t) row ----------------
__global__ __launch_bounds__(256) void ln_kernel(const float* __restrict__ x,
                                                 const float* __restrict__ g,
                                                 const float* __restrict__ bta,
                                                 float* __restrict__ out) {
    __shared__ float red[4];
    int row = blockIdx.x;
    const float* xr = x + (size_t)row * E_;
    int tid = threadIdx.x;
    float v0 = xr[tid], v1 = xr[tid + 256];
    float s = v0 + v1;
    for (int off = 32; off; off >>= 1) s += __shfl_down(s, off, 64);
    if ((tid & 63) == 0) red[tid >> 6] = s;
    __syncthreads();
    float mu = (red[0] + red[1] + red[2] + red[3]) * (1.0f / E_);
    __syncthreads();
    float d0 = v0 - mu, d1 = v1 - mu;
    float sq = d0 * d0 + d1 * d1;
    for (int off = 32; off; off >>= 1) sq += __shfl_down(sq, off, 64);
    if ((tid & 63) == 0) red[tid >> 6] = sq;
    __syncthreads();
    float var = (red[0] + red[1] + red[2] + red[3]) * (1.0f / E_);
    float r = rsqrtf(var + 1e-5f);
    out[(size_t)row * E_ + tid] = g[tid] * d0 * r + bta[tid];
    out[(size_t)row * E_ + tid + 256] = g[tid + 256] * d1 * r + bta[tid + 256];
}

// ---------------- generic tiled GEMM: C(MxN) = A(MxK) * B(KxN) + epilogue ----------
// BHEAD: B is (H,E,D) head-major weight, col n=(h*64+d).
// MSK: multiply row by (rmask[row]!=0).  DORELU: relu.
// OM: 0 = f32 MxN row-major, 1 = f32 BHTD (attention head layout).
// RES: add resid[row*N+col].  BIAS: add bias[col].
template <int BHEAD, int MSK, int DORELU, int OM, int RES, int BIAS>
__global__ __launch_bounds__(256) void gemm_kernel(
    const float* __restrict__ A, const float* __restrict__ Bw,
    const float* __restrict__ bias, const int* __restrict__ rmask,
    const float* __restrict__ resid, float* __restrict__ C,
    int M, int N, int K) {
    __shared__ float As[16][64];
    __shared__ float Bs[16][65];
    int tid = threadIdx.x;
    int tx = tid & 15, ty = tid >> 4;
    int n0 = blockIdx.x * 64, m0 = blockIdx.y * 64;
    float acc[4][4] = {};

    for (int k0 = 0; k0 < K; k0 += 16) {
        #pragma unroll
        for (int i = tid; i < 1024; i += 256) {
            int r = i >> 4, c = i & 15;
            As[c][r] = A[(size_t)(m0 + r) * K + k0 + c];
        }
        #pragma unroll
        for (int i = tid; i < 1024; i += 256) {
            int r = i >> 6, c = i & 63;
            size_t addr;
            if (BHEAD) {
                int h = n0 >> 6;  // tile is 64-wide & 64-aligned => single head
                addr = (size_t)h * K * 64 + (size_t)(k0 + r) * 64 + c;
            } else {
                addr = (size_t)(k0 + r) * N + n0 + c;
            }
            Bs[r][c] = Bw[addr];
        }
        __syncthreads();
        #pragma unroll
        for (int kk = 0; kk < 16; ++kk) {
            float a[4], b[4];
            #pragma unroll
            for (int i = 0; i < 4; ++i) a[i] = As[kk][ty * 4 + i];
            #pragma unroll
            for (int j = 0; j < 4; ++j) b[j] = Bs[kk][tx * 4 + j];
            #pragma unroll
            for (int i = 0; i < 4; ++i)
                #pragma unroll
                for (int j = 0; j < 4; ++j) acc[i][j] += a[i] * b[j];
        }
        __syncthreads();
    }

    #pragma unroll
    for (int i = 0; i < 4; ++i) {
        int row = m0 + ty * 4 + i;
        float mval = 1.0f;
        if (MSK) mval = (rmask[row] != 0) ? 1.0f : 0.0f;
        #pragma unroll
        for (int j = 0; j < 4; ++j) {
            int col = n0 + tx * 4 + j;
            float val = acc[i][j];
            if (BIAS) val += bias[col];
            if (MSK) val *= mval;
            if (DORELU) val = fmaxf(val, 0.0f);
            if (RES) val += resid[(size_t)row * N + col];
            if (OM == 0) {
                C[(size_t)row * N + col] = val;
            } else {
                int b_ = row / T_, t = row % T_;
                int h = col >> 6, d = col & 63;
                C[(((size_t)b_ * H_ + h) * T_ + t) * D_ + d] = val;
            }
        }
    }
}

// ---------------- causal attention, one wave per (b,h,t) ----------------
// q,k,v: (B,H,T,D) f32.  o: (B,T,E) f32 with e = h*64+d.
__global__ __launch_bounds__(64) void attn_kernel(const float* __restrict__ q,
                                                  const float* __restrict__ k,
                                                  const float* __restrict__ v,
                                                  float* __restrict__ o) {
    int t = blockIdx.x, h = blockIdx.y, b = blockIdx.z;
    int lane = threadIdx.x;
    const size_t bh = ((size_t)b * H_ + h) * T_ * D_;
    const float* qp = q + bh + (size_t)t * D_;
    const float* kp = k + bh;
    const float* vp = v + bh;
    __shared__ float sc[T_];
    float qd = qp[lane];
    for (int s = 0; s <= t; ++s) {
        float p = qd * kp[s * D_ + lane];
        for (int off = 32; off; off >>= 1) p += __shfl_down(p, off, 64);
        if (lane == 0) sc[s] = p * SCALE;
    }
    __syncthreads();
    float mx = -1e30f;
    for (int s = lane; s <= t; s += 64) mx = fmaxf(mx, sc[s]);
    for (int off = 32; off; off >>= 1) mx = fmaxf(mx, __shfl_xor(mx, off, 64));
    float sum = 0.f;
    for (int s = lane; s <= t; s += 64) {
        float e = __expf(sc[s] - mx);
        sc[s] = e;
        sum += e;
    }
    for (int off = 32; off; off >>= 1) sum += __shfl_xor(sum, off, 64);
    __syncthreads();
    float inv = 1.0f / sum;
    float acc = 0.f;
    for (int s = 0; s <= t; ++s) acc += sc[s] * vp[s * D_ + lane];
    o[((size_t)b * T_ + t) * E_ + h * D_ + lane] = acc * inv;
}

extern "C" void kernel_launch(void* const* d_in, const int* in_sizes, int n_in,
                              void* d_out, int out_size, void* d_ws, size_t ws_size,
                              hipStream_t stream) {
    const float* idx    = (const float*)d_in[0];
    const float* memory = (const float*)d_in[1];
    const int* src_mask  = (const int*)d_in[2];
    const int* pred_mask = (const int*)d_in[3];
    const float* sa_wq = (const float*)d_in[4];
    const float* sa_wk = (const float*)d_in[5];
    const float* sa_wv = (const float*)d_in[6];
    const float* sa_wo = (const float*)d_in[7];
    const float* sa_bo = (const float*)d_in[8];
    const float* ca_wq = (const float*)d_in[9];
    const float* ca_wk = (const float*)d_in[10];
    const float* ca_wv = (const float*)d_in[11];
    const float* ca_wo = (const float*)d_in[12];
    const float* ca_bo = (const float*)d_in[13];
    const float* f_w1  = (const float*)d_in[14];
    const float* f_b1  = (const float*)d_in[15];
    const float* f_w2  = (const float*)d_in[16];
    const float* f_b2  = (const float*)d_in[17];
    const float* ln1_g = (const float*)d_in[18];
    const float* ln1_b = (const float*)d_in[19];
    const float* ln2_g = (const float*)d_in[20];
    const float* ln2_b = (const float*)d_in[21];
    const float* ln3_g = (const float*)d_in[22];
    const float* ln3_b = (const float*)d_in[23];
    float* out = (float*)d_out;

    const size_t BTE = (size_t)B_ * T_ * E_;  // 6,553,600
    // 5 f32 scratch slots (131 MB); d_out doubles as the x2 buffer.
    float* b0 = (float*)d_ws;
    float* b1 = b0 + BTE;
    float* b2 = b1 + BTE;
    float* b3 = b2 + BTE;
    float* b4 = b3 + BTE;

    const int M = B_ * T_;  // 12800
    dim3 blk(256);
    dim3 g512(E_ / 64, M / 64);       // (8, 200)
    dim3 g2048(4 * E_ / 64, M / 64);  // (32, 200)
    dim3 gattn(T_, H_, B_);

    // h1 = LN(idx, ln1)                       -> b0
    ln_kernel<<<M, 256, 0, stream>>>(idx, ln1_g, ln1_b, b0);
    // q1 = mask_pm(h1 @ sa_wq)  (BHTD)        -> b1
    gemm_kernel<1,1,0,1,0,0><<<g512, blk, 0, stream>>>(b0, sa_wq, nullptr, pred_mask, nullptr, b1, M, E_, E_);
    // k1 = mask_pm(h1 @ sa_wk)                -> b2
    gemm_kernel<1,1,0,1,0,0><<<g512, blk, 0, stream>>>(b0, sa_wk, nullptr, pred_mask, nullptr, b2, M, E_, E_);
    // v1 = h1 @ sa_wv                         -> b3
    gemm_kernel<1,0,0,1,0,0><<<g512, blk, 0, stream>>>(b0, sa_wv, nullptr, nullptr, nullptr, b3, M, E_, E_);
    // o1 = attn(q1,k1,v1)  (BTE)              -> b4
    attn_kernel<<<gattn, 64, 0, stream>>>(b1, b2, b3, b4);
    // x1 = o1 @ sa_wo + sa_bo + idx           -> b0
    gemm_kernel<0,0,0,0,1,1><<<g512, blk, 0, stream>>>(b4, sa_wo, sa_bo, nullptr, idx, b0, M, E_, E_);
    // h2 = LN(x1, ln2)                        -> b1
    ln_kernel<<<M, 256, 0, stream>>>(b0, ln2_g, ln2_b, b1);
    // q2 = h2 @ ca_wq                         -> b2
    gemm_kernel<1,0,0,1,0,0><<<g512, blk, 0, stream>>>(b1, ca_wq, nullptr, nullptr, nullptr, b2, M, E_, E_);
    // k2 = mask_sm(memory @ ca_wk)            -> b3
    gemm_kernel<1,1,0,1,0,0><<<g512, blk, 0, stream>>>(memory, ca_wk, nullptr, src_mask, nullptr, b3, M, E_, E_);
    // v2 = h2 @ ca_wv                         -> b4
    gemm_kernel<1,0,0,1,0,0><<<g512, blk, 0, stream>>>(b1, ca_wv, nullptr, nullptr, nullptr, b4, M, E_, E_);
    // o2 = attn(q2,k2,v2)                     -> b1
    attn_kernel<<<gattn, 64, 0, stream>>>(b2, b3, b4, b1);
    // x2 = o2 @ ca_wo + ca_bo + x1            -> d_out (scratch use)
    gemm_kernel<0,0,0,0,1,1><<<g512, blk, 0, stream>>>(b1, ca_wo, ca_bo, nullptr, b0, out, M, E_, E_);
    // h3 = LN(x2, ln3)                        -> b0
    ln_kernel<<<M, 256, 0, stream>>>(out, ln3_g, ln3_b, b0);
    // ff = relu(h3 @ f_w1 + f_b1)             -> b1 (spans b1..b4)
    gemm_kernel<0,0,1,0,0,1><<<g2048, blk, 0, stream>>>(b0, f_w1, f_b1, nullptr, nullptr, b1, M, 4 * E_, E_);
    // out = ff @ f_w2 + f_b2 + x2             -> d_out (in-place residual, per-element RMW)
    gemm_kernel<0,0,0,0,1,1><<<g512, blk, 0, stream>>>(b1, f_w2, f_b2, nullptr, out, out, M, E_, 4 * E_);
}

// Round 3
// 2125.258 us; speedup vs baseline: 2.1725x; 2.1725x over previous
//
#include <hip/hip_runtime.h>
#include <hip/hip_bf16.h>

#define B_ 64
#define T_ 200
#define E_ 512
#define H_ 8
#define D_ 64

static constexpr float SCALE = 0.044194173824159216f;  // 512^-0.5

typedef __attribute__((ext_vector_type(8))) short bf16x8;
typedef __attribute__((ext_vector_type(4))) float f32x4;

// ---------------- f32 -> bf16 convert ----------------
__global__ void conv_kernel(const float* __restrict__ in,
                            __hip_bfloat16* __restrict__ out, int n) {
    int i = blockIdx.x * blockDim.x + threadIdx.x;
    if (i < n) out[i] = __float2bfloat16(in[i]);
}

// ---------------- weight transpose+convert to (N,K) bf16 ----------------
// MODE 0: input (K,N) f32.  MODE 1: input (H,K,D) f32, N = H*64, n = h*64+d.
template <int MODE>
__global__ void wt_kernel(const float* __restrict__ in,
                          __hip_bfloat16* __restrict__ out, int N, int K) {
    int i = blockIdx.x * blockDim.x + threadIdx.x;
    if (i >= N * K) return;
    int n = i / K, k = i - n * K;
    float v;
    if (MODE == 0) {
        v = in[(size_t)k * N + n];
    } else {
        int h = n >> 6, d = n & 63;
        v = in[((size_t)h * K + k) * 64 + d];
    }
    out[i] = __float2bfloat16(v);
}

// ---------------- LayerNorm over E=512 -> bf16 out, one block per row ----------------
__global__ __launch_bounds__(256) void ln_kernel(const float* __restrict__ x,
                                                 const float* __restrict__ g,
                                                 const float* __restrict__ bta,
                                                 __hip_bfloat16* __restrict__ out) {
    __shared__ float red[4];
    int row = blockIdx.x;
    const float* xr = x + (size_t)row * E_;
    int tid = threadIdx.x;
    float v0 = xr[tid], v1 = xr[tid + 256];
    float s = v0 + v1;
    for (int off = 32; off; off >>= 1) s += __shfl_down(s, off, 64);
    if ((tid & 63) == 0) red[tid >> 6] = s;
    __syncthreads();
    float mu = (red[0] + red[1] + red[2] + red[3]) * (1.0f / E_);
    __syncthreads();
    float d0 = v0 - mu, d1 = v1 - mu;
    float sq = d0 * d0 + d1 * d1;
    for (int off = 32; off; off >>= 1) sq += __shfl_down(sq, off, 64);
    if ((tid & 63) == 0) red[tid >> 6] = sq;
    __syncthreads();
    float var = (red[0] + red[1] + red[2] + red[3]) * (1.0f / E_);
    float r = rsqrtf(var + 1e-5f);
    out[(size_t)row * E_ + tid] = __float2bfloat16(g[tid] * d0 * r + bta[tid]);
    out[(size_t)row * E_ + tid + 256] =
        __float2bfloat16(g[tid + 256] * d1 * r + bta[tid + 256]);
}

// ---------------- MFMA bf16 GEMM: C(MxN) = A(MxK) * BT(NxK)^T + epilogue --------
// 128x128 tile, BK=32, 256 threads (4 waves, each 64x64 via 4x4 of 16x16x32 MFMA).
// MSK: multiply row by (rmask[row]!=0).  RELU: relu.
// OM: 0 = f32 MxN, 1 = f32 BHTD, 2 = bf16 MxN.
// RES: add resid[row*N+col] (f32).  BIAS: add bias[col] (f32).
template <int MSK, int RELU, int OM, int RES, int BIAS>
__global__ __launch_bounds__(256) void mgemm_kernel(
    const short* __restrict__ A, const short* __restrict__ BT,
    const float* __restrict__ bias, const int* __restrict__ rmask,
    const float* __restrict__ resid, void* __restrict__ Cv,
    int M, int N, int K) {
    __shared__ short As[128 * 32];
    __shared__ short Bs[128 * 32];
    int tid = threadIdx.x;
    int wave = tid >> 6, lane = tid & 63;
    int q = lane >> 4, l15 = lane & 15;
    int m0 = blockIdx.y * 128, n0 = blockIdx.x * 128;
    int wm = (wave & 1) * 64, wn = (wave >> 1) * 64;

    int sr = tid >> 2;            // staging row 0..63
    int sc = (tid & 3) * 8;       // staging k-chunk
    f32x4 acc[4][4] = {};

    for (int k0 = 0; k0 < K; k0 += 32) {
        // stage A tile (128x32) and BT tile (128x32), 16B per thread x2
        #pragma unroll
        for (int half = 0; half < 2; ++half) {
            int r = sr + half * 64;
            *(bf16x8*)(&As[r * 32 + sc]) =
                *(const bf16x8*)(&A[(size_t)(m0 + r) * K + k0 + sc]);
            *(bf16x8*)(&Bs[r * 32 + sc]) =
                *(const bf16x8*)(&BT[(size_t)(n0 + r) * K + k0 + sc]);
        }
        __syncthreads();
        bf16x8 af[4], bfr[4];
        #pragma unroll
        for (int i = 0; i < 4; ++i)
            af[i] = *(bf16x8*)(&As[(wm + i * 16 + l15) * 32 + q * 8]);
        #pragma unroll
        for (int j = 0; j < 4; ++j)
            bfr[j] = *(bf16x8*)(&Bs[(wn + j * 16 + l15) * 32 + q * 8]);
        #pragma unroll
        for (int i = 0; i < 4; ++i)
            #pragma unroll
            for (int j = 0; j < 4; ++j)
                acc[i][j] = __builtin_amdgcn_mfma_f32_16x16x32_bf16(
                    af[i], bfr[j], acc[i][j], 0, 0, 0);
        __syncthreads();
    }

    #pragma unroll
    for (int i = 0; i < 4; ++i) {
        #pragma unroll
        for (int r = 0; r < 4; ++r) {
            int row = m0 + wm + i * 16 + q * 4 + r;
            float mval = 1.0f;
            if (MSK) mval = (rmask[row] != 0) ? 1.0f : 0.0f;
            #pragma unroll
            for (int j = 0; j < 4; ++j) {
                int col = n0 + wn + j * 16 + l15;
                float val = acc[i][j][r];
                if (BIAS) val += bias[col];
                if (MSK) val *= mval;
                if (RELU) val = fmaxf(val, 0.0f);
                if (RES) val += resid[(size_t)row * N + col];
                if (OM == 0) {
                    ((float*)Cv)[(size_t)row * N + col] = val;
                } else if (OM == 1) {
                    int b_ = row / T_, t = row % T_;
                    int h = col >> 6, d = col & 63;
                    ((float*)Cv)[(((size_t)b_ * H_ + h) * T_ + t) * D_ + d] = val;
                } else {
                    ((__hip_bfloat16*)Cv)[(size_t)row * N + col] =
                        __float2bfloat16(val);
                }
            }
        }
    }
}

// ---------------- causal attention, one wave per (b,h,t), bf16 out --------------
// q,k,v: (B,H,T,D) f32.  o: (B,T,E) bf16 with e = h*64+d.
__global__ __launch_bounds__(64) void attn_kernel(const float* __restrict__ q,
                                                  const float* __restrict__ k,
                                                  const float* __restrict__ v,
                                                  __hip_bfloat16* __restrict__ o) {
    int t = blockIdx.x, h = blockIdx.y, b = blockIdx.z;
    int lane = threadIdx.x;
    const size_t bh = ((size_t)b * H_ + h) * T_ * D_;
    const float* qp = q + bh + (size_t)t * D_;
    const float* kp = k + bh;
    const float* vp = v + bh;
    __shared__ float sc[T_];
    float qd = qp[lane];
    for (int s = 0; s <= t; ++s) {
        float p = qd * kp[s * D_ + lane];
        for (int off = 32; off; off >>= 1) p += __shfl_down(p, off, 64);
        if (lane == 0) sc[s] = p * SCALE;
    }
    __syncthreads();
    float mx = -1e30f;
    for (int s = lane; s <= t; s += 64) mx = fmaxf(mx, sc[s]);
    for (int off = 32; off; off >>= 1) mx = fmaxf(mx, __shfl_xor(mx, off, 64));
    float sum = 0.f;
    for (int s = lane; s <= t; s += 64) {
        float e = __expf(sc[s] - mx);
        sc[s] = e;
        sum += e;
    }
    for (int off = 32; off; off >>= 1) sum += __shfl_xor(sum, off, 64);
    __syncthreads();
    float inv = 1.0f / sum;
    float acc = 0.f;
    for (int s = 0; s <= t; ++s) acc += sc[s] * vp[s * D_ + lane];
    o[((size_t)b * T_ + t) * E_ + h * D_ + lane] = __float2bfloat16(acc * inv);
}

extern "C" void kernel_launch(void* const* d_in, const int* in_sizes, int n_in,
                              void* d_out, int out_size, void* d_ws, size_t ws_size,
                              hipStream_t stream) {
    const float* idx    = (const float*)d_in[0];
    const float* memory = (const float*)d_in[1];
    const int* src_mask  = (const int*)d_in[2];
    const int* pred_mask = (const int*)d_in[3];
    const float* sa_wq = (const float*)d_in[4];
    const float* sa_wk = (const float*)d_in[5];
    const float* sa_wv = (const float*)d_in[6];
    const float* sa_wo = (const float*)d_in[7];
    const float* sa_bo = (const float*)d_in[8];
    const float* ca_wq = (const float*)d_in[9];
    const float* ca_wk = (const float*)d_in[10];
    const float* ca_wv = (const float*)d_in[11];
    const float* ca_wo = (const float*)d_in[12];
    const float* ca_bo = (const float*)d_in[13];
    const float* f_w1  = (const float*)d_in[14];
    const float* f_b1  = (const float*)d_in[15];
    const float* f_w2  = (const float*)d_in[16];
    const float* f_b2  = (const float*)d_in[17];
    const float* ln1_g = (const float*)d_in[18];
    const float* ln1_b = (const float*)d_in[19];
    const float* ln2_g = (const float*)d_in[20];
    const float* ln2_b = (const float*)d_in[21];
    const float* ln3_g = (const float*)d_in[22];
    const float* ln3_b = (const float*)d_in[23];
    float* out = (float*)d_out;

    const size_t BTE = (size_t)B_ * T_ * E_;  // 6,553,600
    const size_t EE = (size_t)E_ * E_;        // 262,144

    char* p = (char*)d_ws;
    float* qb = (float*)p;            p += BTE * 4;
    float* kb = (float*)p;            p += BTE * 4;
    float* vb = (float*)p;            p += BTE * 4;
    float* x1 = (float*)p;            p += BTE * 4;
    __hip_bfloat16* h_bf   = (__hip_bfloat16*)p; p += BTE * 2;
    __hip_bfloat16* o_bf   = (__hip_bfloat16*)p; p += BTE * 2;
    __hip_bfloat16* mem_bf = (__hip_bfloat16*)p; p += BTE * 2;
    __hip_bfloat16* wT[10];
    for (int i = 0; i < 8; ++i) { wT[i] = (__hip_bfloat16*)p; p += EE * 2; }
    wT[8] = (__hip_bfloat16*)p; p += EE * 4 * 2;  // f_w1T (2048x512)
    wT[9] = (__hip_bfloat16*)p; p += EE * 4 * 2;  // f_w2T (512x2048)
    // ff intermediate (M x 2048 bf16 = 52.4 MB) aliases qb+kb (dead by then)
    __hip_bfloat16* ff_bf = (__hip_bfloat16*)qb;

    const int M = B_ * T_;  // 12800
    dim3 blk(256);
    dim3 g512(E_ / 128, M / 128);      // (4, 100)
    dim3 g2048(4 * E_ / 128, M / 128); // (16, 100)
    dim3 gattn(T_, H_, B_);
    int nw = (int)EE;       // 512*512
    int nw4 = (int)EE * 4;  // 512*2048

    // ---- prep: weight transposes + memory convert ----
    wt_kernel<1><<<(nw + 255) / 256, 256, 0, stream>>>(sa_wq, wT[0], E_, E_);
    wt_kernel<1><<<(nw + 255) / 256, 256, 0, stream>>>(sa_wk, wT[1], E_, E_);
    wt_kernel<1><<<(nw + 255) / 256, 256, 0, stream>>>(sa_wv, wT[2], E_, E_);
    wt_kernel<0><<<(nw + 255) / 256, 256, 0, stream>>>(sa_wo, wT[3], E_, E_);
    wt_kernel<1><<<(nw + 255) / 256, 256, 0, stream>>>(ca_wq, wT[4], E_, E_);
    wt_kernel<1><<<(nw + 255) / 256, 256, 0, stream>>>(ca_wk, wT[5], E_, E_);
    wt_kernel<1><<<(nw + 255) / 256, 256, 0, stream>>>(ca_wv, wT[6], E_, E_);
    wt_kernel<0><<<(nw + 255) / 256, 256, 0, stream>>>(ca_wo, wT[7], E_, E_);
    wt_kernel<0><<<(nw4 + 255) / 256, 256, 0, stream>>>(f_w1, wT[8], 4 * E_, E_);
    wt_kernel<0><<<(nw4 + 255) / 256, 256, 0, stream>>>(f_w2, wT[9], E_, 4 * E_);
    conv_kernel<<<((int)BTE + 255) / 256, 256, 0, stream>>>(memory, mem_bf, (int)BTE);

    // ---- self-attention block ----
    ln_kernel<<<M, 256, 0, stream>>>(idx, ln1_g, ln1_b, h_bf);
    mgemm_kernel<1,0,1,0,0><<<g512, blk, 0, stream>>>((const short*)h_bf, (const short*)wT[0], nullptr, pred_mask, nullptr, qb, M, E_, E_);
    mgemm_kernel<1,0,1,0,0><<<g512, blk, 0, stream>>>((const short*)h_bf, (const short*)wT[1], nullptr, pred_mask, nullptr, kb, M, E_, E_);
    mgemm_kernel<0,0,1,0,0><<<g512, blk, 0, stream>>>((const short*)h_bf, (const short*)wT[2], nullptr, nullptr, nullptr, vb, M, E_, E_);
    attn_kernel<<<gattn, 64, 0, stream>>>(qb, kb, vb, o_bf);
    mgemm_kernel<0,0,0,1,1><<<g512, blk, 0, stream>>>((const short*)o_bf, (const short*)wT[3], sa_bo, nullptr, idx, x1, M, E_, E_);

    // ---- cross-attention block ----
    ln_kernel<<<M, 256, 0, stream>>>(x1, ln2_g, ln2_b, h_bf);
    mgemm_kernel<0,0,1,0,0><<<g512, blk, 0, stream>>>((const short*)h_bf, (const short*)wT[4], nullptr, nullptr, nullptr, qb, M, E_, E_);
    mgemm_kernel<1,0,1,0,0><<<g512, blk, 0, stream>>>((const short*)mem_bf, (const short*)wT[5], nullptr, src_mask, nullptr, kb, M, E_, E_);
    mgemm_kernel<0,0,1,0,0><<<g512, blk, 0, stream>>>((const short*)h_bf, (const short*)wT[6], nullptr, nullptr, nullptr, vb, M, E_, E_);
    attn_kernel<<<gattn, 64, 0, stream>>>(qb, kb, vb, o_bf);
    mgemm_kernel<0,0,0,1,1><<<g512, blk, 0, stream>>>((const short*)o_bf, (const short*)wT[7], ca_bo, nullptr, x1, out, M, E_, E_);

    // ---- feed-forward block ----
    ln_kernel<<<M, 256, 0, stream>>>(out, ln3_g, ln3_b, h_bf);
    mgemm_kernel<0,1,2,0,1><<<g2048, blk, 0, stream>>>((const short*)h_bf, (const short*)wT[8], f_b1, nullptr, nullptr, ff_bf, M, 4 * E_, E_);
    mgemm_kernel<0,0,0,1,1><<<g512, blk, 0, stream>>>((const short*)ff_bf, (const short*)wT[9], f_b2, nullptr, out, out, M, E_, 4 * E_);
}

// Round 4
// 545.298 us; speedup vs baseline: 8.4670x; 3.8974x over previous
//
#include <hip/hip_runtime.h>
#include <hip/hip_bf16.h>

#define B_ 64
#define T_ 200
#define E_ 512
#define H_ 8
#define D_ 64

static constexpr float SCALE = 0.044194173824159216f;  // 512^-0.5

typedef __attribute__((ext_vector_type(8))) short bf16x8;
typedef __attribute__((ext_vector_type(4))) float f32x4;

static __device__ inline short f2bf(float f) {
    __hip_bfloat16 h = __float2bfloat16(f);
    return *(short*)&h;
}

// ---------------- f32 -> bf16 convert ----------------
__global__ void conv_kernel(const float* __restrict__ in,
                            __hip_bfloat16* __restrict__ out, int n) {
    int i = blockIdx.x * blockDim.x + threadIdx.x;
    if (i < n) out[i] = __float2bfloat16(in[i]);
}

// ---------------- weight transpose+convert to (N,K) bf16 ----------------
// MODE 0: input (K,N) f32.  MODE 1: input (H,K,D) f32, N = H*64, n = h*64+d.
template <int MODE>
__global__ void wt_kernel(const float* __restrict__ in,
                          __hip_bfloat16* __restrict__ out, int N, int K) {
    int i = blockIdx.x * blockDim.x + threadIdx.x;
    if (i >= N * K) return;
    int n = i / K, k = i - n * K;
    float v;
    if (MODE == 0) {
        v = in[(size_t)k * N + n];
    } else {
        int h = n >> 6, d = n & 63;
        v = in[((size_t)h * K + k) * 64 + d];
    }
    out[i] = __float2bfloat16(v);
}

// ---------------- LayerNorm over E=512 -> bf16 out, one block per row ----------------
__global__ __launch_bounds__(256) void ln_kernel(const float* __restrict__ x,
                                                 const float* __restrict__ g,
                                                 const float* __restrict__ bta,
                                                 __hip_bfloat16* __restrict__ out) {
    __shared__ float red[4];
    int row = blockIdx.x;
    const float* xr = x + (size_t)row * E_;
    int tid = threadIdx.x;
    float v0 = xr[tid], v1 = xr[tid + 256];
    float s = v0 + v1;
    for (int off = 32; off; off >>= 1) s += __shfl_down(s, off, 64);
    if ((tid & 63) == 0) red[tid >> 6] = s;
    __syncthreads();
    float mu = (red[0] + red[1] + red[2] + red[3]) * (1.0f / E_);
    __syncthreads();
    float d0 = v0 - mu, d1 = v1 - mu;
    float sq = d0 * d0 + d1 * d1;
    for (int off = 32; off; off >>= 1) sq += __shfl_down(sq, off, 64);
    if ((tid & 63) == 0) red[tid >> 6] = sq;
    __syncthreads();
    float var = (red[0] + red[1] + red[2] + red[3]) * (1.0f / E_);
    float r = rsqrtf(var + 1e-5f);
    out[(size_t)row * E_ + tid] = __float2bfloat16(g[tid] * d0 * r + bta[tid]);
    out[(size_t)row * E_ + tid + 256] =
        __float2bfloat16(g[tid + 256] * d1 * r + bta[tid + 256]);
}

// ---------------- MFMA bf16 GEMM: C(MxN) = A(MxK) * BT(NxK)^T + epilogue --------
// 128x128 tile, BK=32, 256 threads (4 waves, each 64x64 via 4x4 of 16x16x32 MFMA).
template <int MSK, int RELU, int OM, int RES, int BIAS>
__global__ __launch_bounds__(256) void mgemm_kernel(
    const short* __restrict__ A, const short* __restrict__ BT,
    const float* __restrict__ bias, const int* __restrict__ rmask,
    const float* __restrict__ resid, void* __restrict__ Cv,
    int M, int N, int K) {
    __shared__ short As[128 * 32];
    __shared__ short Bs[128 * 32];
    int tid = threadIdx.x;
    int wave = tid >> 6, lane = tid & 63;
    int q = lane >> 4, l15 = lane & 15;
    int m0 = blockIdx.y * 128, n0 = blockIdx.x * 128;
    int wm = (wave & 1) * 64, wn = (wave >> 1) * 64;

    int sr = tid >> 2;            // staging row 0..63
    int sc = (tid & 3) * 8;       // staging k-chunk
    f32x4 acc[4][4] = {};

    for (int k0 = 0; k0 < K; k0 += 32) {
        #pragma unroll
        for (int half = 0; half < 2; ++half) {
            int r = sr + half * 64;
            *(bf16x8*)(&As[r * 32 + sc]) =
                *(const bf16x8*)(&A[(size_t)(m0 + r) * K + k0 + sc]);
            *(bf16x8*)(&Bs[r * 32 + sc]) =
                *(const bf16x8*)(&BT[(size_t)(n0 + r) * K + k0 + sc]);
        }
        __syncthreads();
        bf16x8 af[4], bfr[4];
        #pragma unroll
        for (int i = 0; i < 4; ++i)
            af[i] = *(bf16x8*)(&As[(wm + i * 16 + l15) * 32 + q * 8]);
        #pragma unroll
        for (int j = 0; j < 4; ++j)
            bfr[j] = *(bf16x8*)(&Bs[(wn + j * 16 + l15) * 32 + q * 8]);
        #pragma unroll
        for (int i = 0; i < 4; ++i)
            #pragma unroll
            for (int j = 0; j < 4; ++j)
                acc[i][j] = __builtin_amdgcn_mfma_f32_16x16x32_bf16(
                    af[i], bfr[j], acc[i][j], 0, 0, 0);
        __syncthreads();
    }

    #pragma unroll
    for (int i = 0; i < 4; ++i) {
        #pragma unroll
        for (int r = 0; r < 4; ++r) {
            int row = m0 + wm + i * 16 + q * 4 + r;
            float mval = 1.0f;
            if (MSK) mval = (rmask[row] != 0) ? 1.0f : 0.0f;
            #pragma unroll
            for (int j = 0; j < 4; ++j) {
                int col = n0 + wn + j * 16 + l15;
                float val = acc[i][j][r];
                if (BIAS) val += bias[col];
                if (MSK) val *= mval;
                if (RELU) val = fmaxf(val, 0.0f);
                if (RES) val += resid[(size_t)row * N + col];
                if (OM == 0) {
                    ((float*)Cv)[(size_t)row * N + col] = val;
                } else if (OM == 1) {
                    int b_ = row / T_, t = row % T_;
                    int h = col >> 6, d = col & 63;
                    ((float*)Cv)[(((size_t)b_ * H_ + h) * T_ + t) * D_ + d] = val;
                } else {
                    ((__hip_bfloat16*)Cv)[(size_t)row * N + col] =
                        __float2bfloat16(val);
                }
            }
        }
    }
}

// ---------------- MFMA causal attention: one block per (b,h) --------------------
// q,k,v: (B,H,T,D) f32.  o: (B,T,E) bf16, e = h*64+d.
// 13 Q-row tiles of 16 (T=200 padded to 208); K padded to 208, V^T to 224.
// LDS layouts are MFMA-fragment-contiguous: frag reads are 256B bursts, no conflicts.
#define NQT 13
__global__ __launch_bounds__(256) void fattn_kernel(const float* __restrict__ q,
                                                    const float* __restrict__ k,
                                                    const float* __restrict__ v,
                                                    __hip_bfloat16* __restrict__ o) {
    // Kf: [kt 13][g 8][l15 16][j 8]  (g = d/8)                 26,624 B
    // Vf: [nt 4][g 28][l15 16][j 8]  (g = s/8, l15 = d%16)     28,672 B
    // Pb: per-wave P chunk [g 4][m 16][j 8]                     4 * 1,024 B
    __shared__ short Kf[NQT * 8 * 16 * 8];
    __shared__ short Vf[4 * 28 * 16 * 8];
    __shared__ short Pb[4 * 512];

    int tid = threadIdx.x;
    int wave = tid >> 6, lane = tid & 63;
    int qq = lane >> 4, l15 = lane & 15;
    int bh = blockIdx.x;            // b*H + h
    int b = bh >> 3, h = bh & 7;

    const float* kp = k + (size_t)bh * T_ * D_;
    const float* vp = v + (size_t)bh * T_ * D_;
    const float* qp = q + (size_t)bh * T_ * D_;

    // ---- stage K ----
    for (int idx = tid; idx < 8 * 208; idx += 256) {
        int g = idx / 208, s = idx - g * 208;
        int kt = s >> 4, l = s & 15;
        bf16x8 val;
        if (s < 200) {
            const float* src = kp + s * 64 + g * 8;
            #pragma unroll
            for (int j = 0; j < 8; ++j) val[j] = f2bf(src[j]);
        } else {
            #pragma unroll
            for (int j = 0; j < 8; ++j) val[j] = 0;
        }
        *(bf16x8*)&Kf[((kt * 8 + g) * 16 + l) * 8] = val;
    }
    // ---- stage V^T ----
    for (int idx = tid; idx < 28 * 64; idx += 256) {
        int g = idx >> 6, d = idx & 63;
        int nt = d >> 4, dl = d & 15;
        bf16x8 val;
        if (g < 25) {
            #pragma unroll
            for (int j = 0; j < 8; ++j) val[j] = f2bf(vp[(g * 8 + j) * 64 + d]);
        } else {
            #pragma unroll
            for (int j = 0; j < 8; ++j) val[j] = 0;
        }
        *(bf16x8*)&Vf[((nt * 28 + g) * 16 + dl) * 8] = val;
    }
    __syncthreads();

    short* pb = &Pb[wave * 512];

    for (int qt = wave; qt < NQT; qt += 4) {
        int t0 = qt * 16;
        // Q A-frags (direct from global, rows t0+l15; OOB rows land in next ws buffer - harmless)
        bf16x8 qf[2];
        #pragma unroll
        for (int ks = 0; ks < 2; ++ks) {
            const float* src = qp + (t0 + l15) * 64 + ks * 32 + qq * 8;
            #pragma unroll
            for (int j = 0; j < 8; ++j) qf[ks][j] = f2bf(src[j]);
        }
        // ---- S = Q K^T ----
        f32x4 sc[NQT];
        #pragma unroll
        for (int kt = 0; kt < NQT; ++kt) {
            f32x4 a = {0.f, 0.f, 0.f, 0.f};
            bf16x8 kf0 = *(const bf16x8*)&Kf[((kt * 8 + qq) * 16 + l15) * 8];
            bf16x8 kf1 = *(const bf16x8*)&Kf[((kt * 8 + 4 + qq) * 16 + l15) * 8];
            a = __builtin_amdgcn_mfma_f32_16x16x32_bf16(qf[0], kf0, a, 0, 0, 0);
            a = __builtin_amdgcn_mfma_f32_16x16x32_bf16(qf[1], kf1, a, 0, 0, 0);
            sc[kt] = a;
        }
        // ---- scale + causal mask (select: NaN-safe) ----
        #pragma unroll
        for (int kt = 0; kt < NQT; ++kt) {
            #pragma unroll
            for (int r = 0; r < 4; ++r) {
                int col = kt * 16 + l15;
                int rowg = t0 + qq * 4 + r;
                sc[kt][r] = (col <= rowg) ? sc[kt][r] * SCALE : -1e30f;
            }
        }
        // ---- softmax: row max / exp / row sum (rows live in 16 l15 lanes) ----
        float mx[4], sum[4], inv[4];
        #pragma unroll
        for (int r = 0; r < 4; ++r) {
            float m = -1e30f;
            #pragma unroll
            for (int kt = 0; kt < NQT; ++kt) m = fmaxf(m, sc[kt][r]);
            #pragma unroll
            for (int off = 1; off < 16; off <<= 1)
                m = fmaxf(m, __shfl_xor(m, off, 64));
            mx[r] = m;
        }
        #pragma unroll
        for (int r = 0; r < 4; ++r) sum[r] = 0.f;
        #pragma unroll
        for (int kt = 0; kt < NQT; ++kt) {
            #pragma unroll
            for (int r = 0; r < 4; ++r) {
                float e = __expf(sc[kt][r] - mx[r]);
                sc[kt][r] = e;
                sum[r] += e;
            }
        }
        #pragma unroll
        for (int r = 0; r < 4; ++r) {
            float s = sum[r];
            #pragma unroll
            for (int off = 1; off < 16; off <<= 1) s += __shfl_xor(s, off, 64);
            inv[r] = 1.0f / s;
        }
        // ---- O = P V, chunked P->LDS round-trip (32 s per chunk) ----
        f32x4 oa[4] = {};
        #pragma unroll
        for (int c = 0; c < 7; ++c) {
            #pragma unroll
            for (int kt2 = 0; kt2 < 2; ++kt2) {
                int kt = c * 2 + kt2;
                int g = kt2 * 2 + (l15 >> 3);
                int jj = l15 & 7;
                #pragma unroll
                for (int r = 0; r < 4; ++r) {
                    float val = (kt < NQT) ? sc[kt][r] : 0.0f;
                    pb[(g * 16 + qq * 4 + r) * 8 + jj] = f2bf(val);
                }
            }
            bf16x8 pf = *(const bf16x8*)&pb[(qq * 16 + l15) * 8];
            #pragma unroll
            for (int nt = 0; nt < 4; ++nt) {
                bf16x8 vf = *(const bf16x8*)&Vf[((nt * 28 + c * 4 + qq) * 16 + l15) * 8];
                oa[nt] = __builtin_amdgcn_mfma_f32_16x16x32_bf16(pf, vf, oa[nt], 0, 0, 0);
            }
        }
        // ---- store O (scaled by 1/l) ----
        #pragma unroll
        for (int nt = 0; nt < 4; ++nt) {
            #pragma unroll
            for (int r = 0; r < 4; ++r) {
                int t = t0 + qq * 4 + r;
                if (t < T_) {
                    int d = nt * 16 + l15;
                    o[((size_t)b * T_ + t) * E_ + h * D_ + d] =
                        __float2bfloat16(oa[nt][r] * inv[r]);
                }
            }
        }
    }
}

extern "C" void kernel_launch(void* const* d_in, const int* in_sizes, int n_in,
                              void* d_out, int out_size, void* d_ws, size_t ws_size,
                              hipStream_t stream) {
    const float* idx    = (const float*)d_in[0];
    const float* memory = (const float*)d_in[1];
    const int* src_mask  = (const int*)d_in[2];
    const int* pred_mask = (const int*)d_in[3];
    const float* sa_wq = (const float*)d_in[4];
    const float* sa_wk = (const float*)d_in[5];
    const float* sa_wv = (const float*)d_in[6];
    const float* sa_wo = (const float*)d_in[7];
    const float* sa_bo = (const float*)d_in[8];
    const float* ca_wq = (const float*)d_in[9];
    const float* ca_wk = (const float*)d_in[10];
    const float* ca_wv = (const float*)d_in[11];
    const float* ca_wo = (const float*)d_in[12];
    const float* ca_bo = (const float*)d_in[13];
    const float* f_w1  = (const float*)d_in[14];
    const float* f_b1  = (const float*)d_in[15];
    const float* f_w2  = (const float*)d_in[16];
    const float* f_b2  = (const float*)d_in[17];
    const float* ln1_g = (const float*)d_in[18];
    const float* ln1_b = (const float*)d_in[19];
    const float* ln2_g = (const float*)d_in[20];
    const float* ln2_b = (const float*)d_in[21];
    const float* ln3_g = (const float*)d_in[22];
    const float* ln3_b = (const float*)d_in[23];
    float* out = (float*)d_out;

    const size_t BTE = (size_t)B_ * T_ * E_;  // 6,553,600
    const size_t EE = (size_t)E_ * E_;        // 262,144

    char* p = (char*)d_ws;
    float* qb = (float*)p;            p += BTE * 4;
    float* kb = (float*)p;            p += BTE * 4;
    float* vb = (float*)p;            p += BTE * 4;
    float* x1 = (float*)p;            p += BTE * 4;
    __hip_bfloat16* h_bf   = (__hip_bfloat16*)p; p += BTE * 2;
    __hip_bfloat16* o_bf   = (__hip_bfloat16*)p; p += BTE * 2;
    __hip_bfloat16* mem_bf = (__hip_bfloat16*)p; p += BTE * 2;
    __hip_bfloat16* wT[10];
    for (int i = 0; i < 8; ++i) { wT[i] = (__hip_bfloat16*)p; p += EE * 2; }
    wT[8] = (__hip_bfloat16*)p; p += EE * 4 * 2;  // f_w1T (2048x512)
    wT[9] = (__hip_bfloat16*)p; p += EE * 4 * 2;  // f_w2T (512x2048)
    __hip_bfloat16* ff_bf = (__hip_bfloat16*)qb;  // aliases qb+kb (dead by then)

    const int M = B_ * T_;  // 12800
    dim3 blk(256);
    dim3 g512(E_ / 128, M / 128);      // (4, 100)
    dim3 g2048(4 * E_ / 128, M / 128); // (16, 100)
    int nw = (int)EE;
    int nw4 = (int)EE * 4;

    // ---- prep: weight transposes + memory convert ----
    wt_kernel<1><<<(nw + 255) / 256, 256, 0, stream>>>(sa_wq, wT[0], E_, E_);
    wt_kernel<1><<<(nw + 255) / 256, 256, 0, stream>>>(sa_wk, wT[1], E_, E_);
    wt_kernel<1><<<(nw + 255) / 256, 256, 0, stream>>>(sa_wv, wT[2], E_, E_);
    wt_kernel<0><<<(nw + 255) / 256, 256, 0, stream>>>(sa_wo, wT[3], E_, E_);
    wt_kernel<1><<<(nw + 255) / 256, 256, 0, stream>>>(ca_wq, wT[4], E_, E_);
    wt_kernel<1><<<(nw + 255) / 256, 256, 0, stream>>>(ca_wk, wT[5], E_, E_);
    wt_kernel<1><<<(nw + 255) / 256, 256, 0, stream>>>(ca_wv, wT[6], E_, E_);
    wt_kernel<0><<<(nw + 255) / 256, 256, 0, stream>>>(ca_wo, wT[7], E_, E_);
    wt_kernel<0><<<(nw4 + 255) / 256, 256, 0, stream>>>(f_w1, wT[8], 4 * E_, E_);
    wt_kernel<0><<<(nw4 + 255) / 256, 256, 0, stream>>>(f_w2, wT[9], E_, 4 * E_);
    conv_kernel<<<((int)BTE + 255) / 256, 256, 0, stream>>>(memory, mem_bf, (int)BTE);

    // ---- self-attention block ----
    ln_kernel<<<M, 256, 0, stream>>>(idx, ln1_g, ln1_b, h_bf);
    mgemm_kernel<1,0,1,0,0><<<g512, blk, 0, stream>>>((const short*)h_bf, (const short*)wT[0], nullptr, pred_mask, nullptr, qb, M, E_, E_);
    mgemm_kernel<1,0,1,0,0><<<g512, blk, 0, stream>>>((const short*)h_bf, (const short*)wT[1], nullptr, pred_mask, nullptr, kb, M, E_, E_);
    mgemm_kernel<0,0,1,0,0><<<g512, blk, 0, stream>>>((const short*)h_bf, (const short*)wT[2], nullptr, nullptr, nullptr, vb, M, E_, E_);
    fattn_kernel<<<B_ * H_, 256, 0, stream>>>(qb, kb, vb, o_bf);
    mgemm_kernel<0,0,0,1,1><<<g512, blk, 0, stream>>>((const short*)o_bf, (const short*)wT[3], sa_bo, nullptr, idx, x1, M, E_, E_);

    // ---- cross-attention block ----
    ln_kernel<<<M, 256, 0, stream>>>(x1, ln2_g, ln2_b, h_bf);
    mgemm_kernel<0,0,1,0,0><<<g512, blk, 0, stream>>>((const short*)h_bf, (const short*)wT[4], nullptr, nullptr, nullptr, qb, M, E_, E_);
    mgemm_kernel<1,0,1,0,0><<<g512, blk, 0, stream>>>((const short*)mem_bf, (const short*)wT[5], nullptr, src_mask, nullptr, kb, M, E_, E_);
    mgemm_kernel<0,0,1,0,0><<<g512, blk, 0, stream>>>((const short*)h_bf, (const short*)wT[6], nullptr, nullptr, nullptr, vb, M, E_, E_);
    fattn_kernel<<<B_ * H_, 256, 0, stream>>>(qb, kb, vb, o_bf);
    mgemm_kernel<0,0,0,1,1><<<g512, blk, 0, stream>>>((const short*)o_bf, (const short*)wT[7], ca_bo, nullptr, x1, out, M, E_, E_);

    // ---- feed-forward block ----
    ln_kernel<<<M, 256, 0, stream>>>(out, ln3_g, ln3_b, h_bf);
    mgemm_kernel<0,1,2,0,1><<<g2048, blk, 0, stream>>>((const short*)h_bf, (const short*)wT[8], f_b1, nullptr, nullptr, ff_bf, M, 4 * E_, E_);
    mgemm_kernel<0,0,0,1,1><<<g512, blk, 0, stream>>>((const short*)ff_bf, (const short*)wT[9], f_b2, nullptr, out, out, M, E_, 4 * E_);
}